// Round 9
// baseline (421.724 us; speedup 1.0000x reference)
//
#include <hip/hip_runtime.h>
#include <hip/hip_bf16.h>
#include <math.h>

#define BB 2
#define NN 32768
#define KK 16
#define DD 256
#define AA 64
#define VV 64

typedef __attribute__((ext_vector_type(8))) short bf16x8;
typedef __attribute__((ext_vector_type(4))) float f32x4;
typedef __attribute__((ext_vector_type(4))) unsigned short u16x4;

__device__ __forceinline__ ushort f2bf(float v) {
  __hip_bfloat16 b = __float2bfloat16(v);
  ushort u; __builtin_memcpy(&u, &b, 2);
  return u;
}
__device__ __forceinline__ float bflo(unsigned u) { return __uint_as_float(u << 16); }
__device__ __forceinline__ float bfhi(unsigned u) { return __uint_as_float(u & 0xffff0000u); }

// swizzled bf16 tile helpers (row stride 128B, XOR swizzle (row&7)<<4)
__device__ __forceinline__ void astore(ushort* A, int row, int col, float v) {
  int off = (row * 128 + col * 2) ^ ((row & 7) << 4);
  *reinterpret_cast<ushort*>(reinterpret_cast<char*>(A) + off) = f2bf(v);
}
__device__ __forceinline__ bf16x8 afrag(const ushort* A, int rowbase, int lane, int ks) {
  int row = rowbase + (lane & 15), g = lane >> 4;
  int off = (row * 128 + ks * 64 + g * 16) ^ ((row & 7) << 4);
  return *reinterpret_cast<const bf16x8*>(reinterpret_cast<const char*>(A) + off);
}
__device__ __forceinline__ bf16x8 loadfrag(const ushort* p, int fi, int lane) {
  return *reinterpret_cast<const bf16x8*>(&p[((size_t)fi * 64 + lane) * 8]);
}

// ---------------- Kernel 0: pack weights into bf16 B-fragment order ----------------
__global__ __launch_bounds__(256) void k_prep(
    const float* __restrict__ Wq, const float* __restrict__ Wk, const float* __restrict__ Wv,
    const float* __restrict__ Wf1, const float* __restrict__ Wf2,
    const float* __restrict__ Wpa2, const float* __restrict__ Wpv2,
    const float* __restrict__ Ws1, const float* __restrict__ Wo,
    const float* __restrict__ Wpa1, const float* __restrict__ Wpv1,
    ushort* __restrict__ pQKV, ushort* __restrict__ pWf1, ushort* __restrict__ pWf2,
    ushort* __restrict__ pS, ushort* __restrict__ pWo) {
  int tid = blockIdx.x * 256 + threadIdx.x;
  int lane = tid & 63, g = lane >> 4, c16 = lane & 15;
  bf16x8 f;
  if (tid < 6144) {                       // QKV: 8 ks x 12 nt
    int fi = tid >> 6; int ks = fi / 12, nt = fi % 12;
    int col = nt * 16 + c16;
    const float* W = (col < 64) ? Wq : (col < 128) ? Wk : Wv;
    int c = col & 63;
#pragma unroll
    for (int e = 0; e < 8; e++) f[e] = (short)f2bf(W[(ks * 32 + g * 8 + e) * 64 + c]);
    *reinterpret_cast<bf16x8*>(&pQKV[(size_t)tid * 8]) = f;
  } else if (tid < 22528) {               // Wf1: 8 ks x 32 nt
    int t2 = tid - 6144; int fi = t2 >> 6; int ks = fi >> 5, nt = fi & 31;
    int col = nt * 16 + c16;
#pragma unroll
    for (int e = 0; e < 8; e++) f[e] = (short)f2bf(Wf1[(ks * 32 + g * 8 + e) * 512 + col]);
    *reinterpret_cast<bf16x8*>(&pWf1[(size_t)t2 * 8]) = f;
  } else if (tid < 38912) {               // Wf2: 16 ks x 16 nt
    int t3 = tid - 22528; int fi = t3 >> 6; int ks = fi >> 4, nt = fi & 15;
    int col = nt * 16 + c16;
#pragma unroll
    for (int e = 0; e < 8; e++) f[e] = (short)f2bf(Wf2[(ks * 32 + g * 8 + e) * 256 + col]);
    *reinterpret_cast<bf16x8*>(&pWf2[(size_t)t3 * 8]) = f;
  } else if (tid < 40960) {               // pS: {Wpa2,Wpv2,Ws1} x 2ks x 4nt + K-padded {Wpa1,Wpv1} x 4nt
    int t4 = tid - 38912; int fi = t4 >> 6;
    if (fi < 24) {
      int mat = fi >> 3, ks = (fi >> 2) & 1, nt = fi & 3;
      const float* W = (mat == 0) ? Wpa2 : (mat == 1) ? Wpv2 : Ws1;
      int col = nt * 16 + c16;
#pragma unroll
      for (int e = 0; e < 8; e++) f[e] = (short)f2bf(W[(ks * 32 + g * 8 + e) * 64 + col]);
    } else {
      int mat = (fi - 24) >> 2, nt = fi & 3;
      const float* W = mat ? Wpv1 : Wpa1;
      int col = nt * 16 + c16;
#pragma unroll
      for (int e = 0; e < 8; e++) {
        int K = g * 8 + e;
        f[e] = (K < 3) ? (short)f2bf(W[K * 64 + col]) : (short)0;
      }
    }
    *reinterpret_cast<bf16x8*>(&pS[(size_t)t4 * 8]) = f;
  } else if (tid < 43008) {               // pWo: 2 ks x 16 nt
    int t5 = tid - 40960; int fi = t5 >> 6; int ks = fi >> 4, nt = fi & 15;
    int col = nt * 16 + c16;
#pragma unroll
    for (int e = 0; e < 8; e++) f[e] = (short)f2bf(Wo[(ks * 32 + g * 8 + e) * 256 + col]);
    *reinterpret_cast<bf16x8*>(&pWo[(size_t)t5 * 8]) = f;
  }
}

// ---------------- Kernel 1: LN1 + QKV projection (MFMA, bf16 outputs, prefetched) ----------------
__global__ __launch_bounds__(256) void k_qkv(
    const float* __restrict__ x, const float* __restrict__ g1, const float* __restrict__ b1,
    const ushort* __restrict__ pW,
    const float* __restrict__ bq, const float* __restrict__ bk, const float* __restrict__ bv,
    ushort* __restrict__ qo, ushort* __restrict__ ko, ushort* __restrict__ vo) {
  __shared__ __align__(16) ushort hs[32 * 256];
  int t = threadIdx.x, lane = t & 63, w = t >> 6;
  size_t row0 = (size_t)blockIdx.x * 32;

  {
    const float4 gv = *reinterpret_cast<const float4*>(&g1[lane * 4]);
    const float4 bvv = *reinterpret_cast<const float4*>(&b1[lane * 4]);
#pragma unroll
    for (int r8 = 0; r8 < 8; r8++) {
      int r = w * 8 + r8;
      const float4 xv = *reinterpret_cast<const float4*>(&x[(row0 + r) * DD + lane * 4]);
      float s = xv.x + xv.y + xv.z + xv.w;
      float s2 = xv.x * xv.x + xv.y * xv.y + xv.z * xv.z + xv.w * xv.w;
      for (int o = 32; o > 0; o >>= 1) { s += __shfl_down(s, o, 64); s2 += __shfl_down(s2, o, 64); }
      s = __shfl(s, 0, 64); s2 = __shfl(s2, 0, 64);
      float m = s * (1.f / DD), rs = rsqrtf(s2 * (1.f / DD) - m * m + 1e-5f);
      u16x4 hv;
      hv[0] = f2bf((xv.x - m) * rs * gv.x + bvv.x);
      hv[1] = f2bf((xv.y - m) * rs * gv.y + bvv.y);
      hv[2] = f2bf((xv.z - m) * rs * gv.z + bvv.z);
      hv[3] = f2bf((xv.w - m) * rs * gv.w + bvv.w);
      int off = (r * 512 + lane * 8) ^ ((r & 7) << 4);
      *reinterpret_cast<u16x4*>(reinterpret_cast<char*>(hs) + off) = hv;
    }
  }
  __syncthreads();

  f32x4 acc[2][3] = {};
  bf16x8 fw[3][3];
  int rowa = lane & 15, gg = lane >> 4;
#pragma unroll
  for (int p = 0; p < 2; p++)
#pragma unroll
    for (int j = 0; j < 3; j++) fw[p][j] = loadfrag(pW, p * 12 + w * 3 + j, lane);
#pragma unroll
  for (int ks = 0; ks < 8; ks++) {
    if (ks + 2 < 8) {
#pragma unroll
      for (int j = 0; j < 3; j++) fw[(ks + 2) % 3][j] = loadfrag(pW, (ks + 2) * 12 + w * 3 + j, lane);
    }
    bf16x8 a0 = *reinterpret_cast<const bf16x8*>(reinterpret_cast<const char*>(hs) +
                 ((rowa * 512 + ks * 64 + gg * 16) ^ ((rowa & 7) << 4)));
    bf16x8 a1 = *reinterpret_cast<const bf16x8*>(reinterpret_cast<const char*>(hs) +
                 (((rowa + 16) * 512 + ks * 64 + gg * 16) ^ ((rowa & 7) << 4)));
#pragma unroll
    for (int j = 0; j < 3; j++) {
      acc[0][j] = __builtin_amdgcn_mfma_f32_16x16x32_bf16(a0, fw[ks % 3][j], acc[0][j], 0, 0, 0);
      acc[1][j] = __builtin_amdgcn_mfma_f32_16x16x32_bf16(a1, fw[ks % 3][j], acc[1][j], 0, 0, 0);
    }
  }

#pragma unroll
  for (int j = 0; j < 3; j++) {
    int ntg = w * 3 + j;
    int buf = ntg >> 2;
    ushort* out = (buf == 0) ? qo : (buf == 1) ? ko : vo;
    const float* bias = (buf == 0) ? bq : (buf == 1) ? bk : bv;
    int col = (ntg & 3) * 16 + (lane & 15);
    float bb = bias[col];
#pragma unroll
    for (int mt = 0; mt < 2; mt++)
#pragma unroll
      for (int r = 0; r < 4; r++) {
        int row = mt * 16 + (lane >> 4) * 4 + r;
        out[(row0 + row) * 64 + col] = f2bf(acc[mt][j][r] + bb);
      }
  }
}

// ---------------- Kernel 2: attention, register-resident ra/rv ----------------
__global__ __launch_bounds__(256) void k_attn(
    const float* __restrict__ x, const float* __restrict__ relpos, const int* __restrict__ knn,
    const ushort* __restrict__ qg, const ushort* __restrict__ kg, const ushort* __restrict__ vg,
    const float* __restrict__ bpa1, const float* __restrict__ bpa2,
    const float* __restrict__ bpv1, const float* __restrict__ bpv2,
    const ushort* __restrict__ pS, const float* __restrict__ bs1,
    const float* __restrict__ Ws2, const float* __restrict__ bs2,
    const ushort* __restrict__ pWo, const float* __restrict__ bo,
    float* __restrict__ xmid) {
  int n0 = blockIdx.x * 2;
  int t = threadIdx.x, lane = t & 63, w = t >> 6;
  int g = lane >> 4, c16 = lane & 15;
  int col = w * 16 + c16;   // each thread owns one column for P2/P3/P4/P6

  __shared__ __align__(16) ushort A0[64 * 64];      // 8KB hidden tiles (P1 out, P2 in)
  __shared__ __align__(16) ushort TT[64 * 64];      // 8KB tanh tile (P3 out, P4 in)
  __shared__ __align__(16) ushort hid_bs[64][72];   // 9KB bf16 score partials
  __shared__ __align__(16) ushort RP[32 * 32];      // 2KB K-padded relpos
  __shared__ __align__(16) ushort ctile[16 * 64];   // 2KB
  __shared__ float attn_s[64];
  __shared__ int idx_s[2][16];

  // ---- P0: idx + RP staging ----
  if (t < 32) {
    idx_s[t >> 4][t & 15] = knn[(n0 + (t >> 4)) * KK + (t & 15)];
    float r0 = relpos[(size_t)n0 * 48 + t * 3 + 0];
    float r1 = relpos[(size_t)n0 * 48 + t * 3 + 1];
    float r2 = relpos[(size_t)n0 * 48 + t * 3 + 2];
    uint4 z; z.x = 0; z.y = 0; z.z = 0; z.w = 0;
    uint4 f0;
    f0.x = ((unsigned)f2bf(r1) << 16) | (unsigned)f2bf(r0);
    f0.y = (unsigned)f2bf(r2);
    f0.z = 0; f0.w = 0;
    *reinterpret_cast<uint4*>(&RP[t * 32 + 0])  = f0;
    *reinterpret_cast<uint4*>(&RP[t * 32 + 8])  = z;
    *reinterpret_cast<uint4*>(&RP[t * 32 + 16]) = z;
    *reinterpret_cast<uint4*>(&RP[t * 32 + 24]) = z;
  }
  __syncthreads();

  // ---- prefetch: k-gathers (consumed in P3) + q scalars ----
  ushort ku[2][2][4];   // [pt][b][r], k = g*4+r, this thread's column
  float qf[2][2];       // [pt][b]
#pragma unroll
  for (int pt = 0; pt < 2; pt++)
#pragma unroll
    for (int b = 0; b < 2; b++) {
      qf[pt][b] = bflo((unsigned)qg[((size_t)b * NN + n0 + pt) * AA + col]);
#pragma unroll
      for (int r = 0; r < 4; r++)
        ku[pt][b][r] = kg[((size_t)b * NN + idx_s[pt][g * 4 + r]) * AA + col];
    }

  // ---- P1: rel-pos MLP hidden via K-padded MFMA -> A0 ----
  {
    bf16x8 aRP0 = *reinterpret_cast<const bf16x8*>(&RP[(lane & 15) * 32 + g * 8]);         // pt0
    bf16x8 aRP1 = *reinterpret_cast<const bf16x8*>(&RP[((lane & 15) + 16) * 32 + g * 8]);  // pt1
    bf16x8 bA = loadfrag(pS, 24 + w, lane);
    bf16x8 bV = loadfrag(pS, 28 + w, lane);
    float ba = bpa1[col], bv1_ = bpv1[col];
    f32x4 zz = {0.f, 0.f, 0.f, 0.f};
    f32x4 hA0 = __builtin_amdgcn_mfma_f32_16x16x32_bf16(aRP0, bA, zz, 0, 0, 0);
    f32x4 hA1 = __builtin_amdgcn_mfma_f32_16x16x32_bf16(aRP1, bA, zz, 0, 0, 0);
    f32x4 hV0 = __builtin_amdgcn_mfma_f32_16x16x32_bf16(aRP0, bV, zz, 0, 0, 0);
    f32x4 hV1 = __builtin_amdgcn_mfma_f32_16x16x32_bf16(aRP1, bV, zz, 0, 0, 0);
#pragma unroll
    for (int r = 0; r < 4; r++) {
      astore(A0, 0  + g * 4 + r, col, fmaxf(hA0[r] + ba, 0.f));
      astore(A0, 16 + g * 4 + r, col, fmaxf(hA1[r] + ba, 0.f));
      astore(A0, 32 + g * 4 + r, col, fmaxf(hV0[r] + bv1_, 0.f));
      astore(A0, 48 + g * 4 + r, col, fmaxf(hV1[r] + bv1_, 0.f));
    }
  }
  __syncthreads();

  // ---- P2: ra/rv = hidden @ {Wpa2,Wpv2} + bias (MFMA) -> REGISTERS ----
  float ra_reg[2][4], rv_reg[2][4];   // [pt][r]: row = pt*16 + g*4 + r, this column
  {
    bf16x8 bwa0 = loadfrag(pS, 0 + w, lane);
    bf16x8 bwa1 = loadfrag(pS, 4 + w, lane);
    bf16x8 bwv0 = loadfrag(pS, 8 + w, lane);
    bf16x8 bwv1 = loadfrag(pS, 12 + w, lane);
    float ba2 = bpa2[col], bv2 = bpv2[col];
#pragma unroll
    for (int mt = 0; mt < 2; mt++) {
      bf16x8 a0 = afrag(A0, mt * 16, lane, 0), a1 = afrag(A0, mt * 16, lane, 1);
      f32x4 acc = {0.f, 0.f, 0.f, 0.f};
      acc = __builtin_amdgcn_mfma_f32_16x16x32_bf16(a0, bwa0, acc, 0, 0, 0);
      acc = __builtin_amdgcn_mfma_f32_16x16x32_bf16(a1, bwa1, acc, 0, 0, 0);
#pragma unroll
      for (int r = 0; r < 4; r++) ra_reg[mt][r] = acc[r] + ba2;
      bf16x8 v0 = afrag(A0, 32 + mt * 16, lane, 0), v1 = afrag(A0, 32 + mt * 16, lane, 1);
      f32x4 accv = {0.f, 0.f, 0.f, 0.f};
      accv = __builtin_amdgcn_mfma_f32_16x16x32_bf16(v0, bwv0, accv, 0, 0, 0);
      accv = __builtin_amdgcn_mfma_f32_16x16x32_bf16(v1, bwv1, accv, 0, 0, 0);
#pragma unroll
      for (int r = 0; r < 4; r++) rv_reg[mt][r] = accv[r] + bv2;
    }
  }
  // no barrier: P3 writes TT, P2 read A0 — disjoint

  // ---- P3: tanh -> TT (row = (pt*2+b)*16 + g*4+r, this column) ----
#pragma unroll
  for (int pt = 0; pt < 2; pt++)
#pragma unroll
    for (int b = 0; b < 2; b++)
#pragma unroll
      for (int r = 0; r < 4; r++) {
        float kf = bflo((unsigned)ku[pt][b][r]);
        float xv = qf[pt][b] - kf + ra_reg[pt][r];
        float tv = 1.f - 2.f * __builtin_amdgcn_rcpf(__expf(2.f * xv) + 1.f);
        astore(TT, (pt * 2 + b) * 16 + g * 4 + r, col, tv);
      }
  __syncthreads();

  // ---- P4: score-hidden MFMA from TT; relu * Ws2[col] -> hid_bs ----
  {
    bf16x8 fsA = loadfrag(pS, 16 + w, lane);
    bf16x8 fsB = loadfrag(pS, 20 + w, lane);
    float bsc = bs1[col], wsc = Ws2[col];
#pragma unroll
    for (int mt = 0; mt < 4; mt++) {
      bf16x8 a0 = afrag(TT, mt * 16, lane, 0), a1 = afrag(TT, mt * 16, lane, 1);
      f32x4 acc = {0.f, 0.f, 0.f, 0.f};
      acc = __builtin_amdgcn_mfma_f32_16x16x32_bf16(a0, fsA, acc, 0, 0, 0);
      acc = __builtin_amdgcn_mfma_f32_16x16x32_bf16(a1, fsB, acc, 0, 0, 0);
#pragma unroll
      for (int r = 0; r < 4; r++)
        hid_bs[mt * 16 + g * 4 + r][col] = f2bf(fmaxf(acc[r] + bsc, 0.f) * wsc);
    }
  }
  __syncthreads();

  // ---- P5: row-sum + softmax over each 16-row group ----
  if (t < 64) {
    const uint4* hrow = reinterpret_cast<const uint4*>(&hid_bs[t][0]);
    float s = 0.f;
#pragma unroll
    for (int c = 0; c < 8; c++) {
      uint4 v4 = hrow[c];
      s += bflo(v4.x) + bfhi(v4.x) + bflo(v4.y) + bfhi(v4.y) +
           bflo(v4.z) + bfhi(v4.z) + bflo(v4.w) + bfhi(v4.w);
    }
    float sc = (s + bs2[0]) * 0.125f;
    float mx = sc;
#pragma unroll
    for (int o = 8; o > 0; o >>= 1) mx = fmaxf(mx, __shfl_xor(mx, o, 64));
    float e = __expf(sc - mx);
    float ss = e;
#pragma unroll
    for (int o = 8; o > 0; o >>= 1) ss += __shfl_xor(ss, o, 64);
    attn_s[t] = e / ss;
  }
  __syncthreads();

  // ---- P6: ctx = attn @ (vn + rv): register rv, cross-g shfl reduce ----
  {
    float cacc[4] = {0.f, 0.f, 0.f, 0.f};
#pragma unroll
    for (int pt = 0; pt < 2; pt++)
#pragma unroll
      for (int b = 0; b < 2; b++) {
        int mt = pt * 2 + b;
        size_t bbase = (size_t)b * NN;
#pragma unroll
        for (int r = 0; r < 4; r++) {
          int k = g * 4 + r;
          float vf = bflo((unsigned)vg[(bbase + idx_s[pt][k]) * VV + col]);
          cacc[mt] += attn_s[mt * 16 + k] * (vf + rv_reg[pt][r]);
        }
      }
#pragma unroll
    for (int mt = 0; mt < 4; mt++) {
      cacc[mt] += __shfl_xor(cacc[mt], 16, 64);
      cacc[mt] += __shfl_xor(cacc[mt], 32, 64);
    }
    if (g == 0) {
#pragma unroll
      for (int mt = 0; mt < 4; mt++) astore(ctile, mt, col, cacc[mt]);
    }
  }
  __syncthreads();

  // ---- P7: xmid = x + ctx @ Wo + bo (MFMA; junk A-rows 4-15 only affect discarded D rows) ----
  {
    bf16x8 a0 = afrag(ctile, 0, lane, 0), a1 = afrag(ctile, 0, lane, 1);
    f32x4 acc[4];
#pragma unroll
    for (int j = 0; j < 4; j++) {
      bf16x8 b0 = loadfrag(pWo, 0 + w * 4 + j, lane);
      bf16x8 b1 = loadfrag(pWo, 16 + w * 4 + j, lane);
      f32x4 a = {0.f, 0.f, 0.f, 0.f};
      a = __builtin_amdgcn_mfma_f32_16x16x32_bf16(a0, b0, a, 0, 0, 0);
      a = __builtin_amdgcn_mfma_f32_16x16x32_bf16(a1, b1, a, 0, 0, 0);
      acc[j] = a;
    }
    if (g == 0) {
#pragma unroll
      for (int j = 0; j < 4; j++) {
        int oc = w * 64 + j * 16 + c16;
        float bb = bo[oc];
#pragma unroll
        for (int r = 0; r < 4; r++) {   // r = mt = pt*2+b
          int pt = r >> 1, b = r & 1;
          size_t addr = ((size_t)b * NN + n0 + pt) * DD + oc;
          xmid[addr] = x[addr] + acc[j][r] + bb;
        }
      }
    }
  }
}

// ---------------- Kernel 3: LN2 + FFN + residual (MFMA, prefetched) ----------------
__global__ __launch_bounds__(256) void k_ffn(
    const float* __restrict__ xmid, const float* __restrict__ g2, const float* __restrict__ b2,
    const ushort* __restrict__ pWf1, const float* __restrict__ bf1,
    const ushort* __restrict__ pWf2, const float* __restrict__ bf2,
    float* __restrict__ out) {
  __shared__ __align__(16) ushort hs[32 * 256];
  __shared__ __align__(16) ushort ys[32 * 512];
  int t = threadIdx.x, lane = t & 63, w = t >> 6;
  size_t row0 = (size_t)blockIdx.x * 32;
  int rowa = lane & 15, gg = lane >> 4;

  {
    const float4 gv = *reinterpret_cast<const float4*>(&g2[lane * 4]);
    const float4 bvv = *reinterpret_cast<const float4*>(&b2[lane * 4]);
#pragma unroll
    for (int r8 = 0; r8 < 8; r8++) {
      int r = w * 8 + r8;
      const float4 xv = *reinterpret_cast<const float4*>(&xmid[(row0 + r) * DD + lane * 4]);
      float s = xv.x + xv.y + xv.z + xv.w;
      float s2 = xv.x * xv.x + xv.y * xv.y + xv.z * xv.z + xv.w * xv.w;
      for (int o = 32; o > 0; o >>= 1) { s += __shfl_down(s, o, 64); s2 += __shfl_down(s2, o, 64); }
      s = __shfl(s, 0, 64); s2 = __shfl(s2, 0, 64);
      float m = s * (1.f / DD), rs = rsqrtf(s2 * (1.f / DD) - m * m + 1e-5f);
      u16x4 hv;
      hv[0] = f2bf((xv.x - m) * rs * gv.x + bvv.x);
      hv[1] = f2bf((xv.y - m) * rs * gv.y + bvv.y);
      hv[2] = f2bf((xv.z - m) * rs * gv.z + bvv.z);
      hv[3] = f2bf((xv.w - m) * rs * gv.w + bvv.w);
      int off = (r * 512 + lane * 8) ^ ((r & 7) << 4);
      *reinterpret_cast<u16x4*>(reinterpret_cast<char*>(hs) + off) = hv;
    }
  }
  __syncthreads();

  // GEMM1: depth-1 double-buffered weight prefetch (fA/fB)
  f32x4 acc1[2][8] = {};
  {
    bf16x8 fA[8], fB[8];
#pragma unroll
    for (int j = 0; j < 8; j++) fA[j] = loadfrag(pWf1, w * 8 + j, lane);
#pragma unroll
    for (int ks = 0; ks < 8; ks += 2) {
#pragma unroll
      for (int j = 0; j < 8; j++) fB[j] = loadfrag(pWf1, (ks + 1) * 32 + w * 8 + j, lane);
      {
        bf16x8 a0 = *reinterpret_cast<const bf16x8*>(reinterpret_cast<const char*>(hs) +
                     ((rowa * 512 + ks * 64 + gg * 16) ^ ((rowa & 7) << 4)));
        bf16x8 a1 = *reinterpret_cast<const bf16x8*>(reinterpret_cast<const char*>(hs) +
                     (((rowa + 16) * 512 + ks * 64 + gg * 16) ^ ((rowa & 7) << 4)));
#pragma unroll
        for (int j = 0; j < 8; j++) {
          acc1[0][j] = __builtin_amdgcn_mfma_f32_16x16x32_bf16(a0, fA[j], acc1[0][j], 0, 0, 0);
          acc1[1][j] = __builtin_amdgcn_mfma_f32_16x16x32_bf16(a1, fA[j], acc1[1][j], 0, 0, 0);
        }
      }
      if (ks + 2 < 8) {
#pragma unroll
        for (int j = 0; j < 8; j++) fA[j] = loadfrag(pWf1, (ks + 2) * 32 + w * 8 + j, lane);
      }
      {
        bf16x8 a0 = *reinterpret_cast<const bf16x8*>(reinterpret_cast<const char*>(hs) +
                     ((rowa * 512 + (ks + 1) * 64 + gg * 16) ^ ((rowa & 7) << 4)));
        bf16x8 a1 = *reinterpret_cast<const bf16x8*>(reinterpret_cast<const char*>(hs) +
                     (((rowa + 16) * 512 + (ks + 1) * 64 + gg * 16) ^ ((rowa & 7) << 4)));
#pragma unroll
        for (int j = 0; j < 8; j++) {
          acc1[0][j] = __builtin_amdgcn_mfma_f32_16x16x32_bf16(a0, fB[j], acc1[0][j], 0, 0, 0);
          acc1[1][j] = __builtin_amdgcn_mfma_f32_16x16x32_bf16(a1, fB[j], acc1[1][j], 0, 0, 0);
        }
      }
    }
  }

#pragma unroll
  for (int j = 0; j < 8; j++) {
    int col = w * 128 + j * 16 + (lane & 15);
    float bb = bf1[col];
#pragma unroll
    for (int mt = 0; mt < 2; mt++)
#pragma unroll
      for (int r = 0; r < 4; r++) {
        float v = acc1[mt][j][r] + bb;
        v = v * 0.5f * (1.f + erff(v * 0.70710678118654752f));
        int row = mt * 16 + (lane >> 4) * 4 + r;
        int off = (row * 1024 + col * 2) ^ ((row & 7) << 4);
        *reinterpret_cast<ushort*>(reinterpret_cast<char*>(ys) + off) = f2bf(v);
      }
  }
  __syncthreads();

  // GEMM2: depth-2 rotating weight prefetch (fully unrolled -> static indices)
  f32x4 acc2[2][4] = {};
  {
    bf16x8 f2[3][4];
#pragma unroll
    for (int p = 0; p < 2; p++)
#pragma unroll
      for (int j = 0; j < 4; j++) f2[p][j] = loadfrag(pWf2, p * 16 + w * 4 + j, lane);
#pragma unroll
    for (int ks = 0; ks < 16; ks++) {
      if (ks + 2 < 16) {
#pragma unroll
        for (int j = 0; j < 4; j++) f2[(ks + 2) % 3][j] = loadfrag(pWf2, (ks + 2) * 16 + w * 4 + j, lane);
      }
      bf16x8 a0 = *reinterpret_cast<const bf16x8*>(reinterpret_cast<const char*>(ys) +
                   ((rowa * 1024 + ks * 64 + gg * 16) ^ ((rowa & 7) << 4)));
      bf16x8 a1 = *reinterpret_cast<const bf16x8*>(reinterpret_cast<const char*>(ys) +
                   (((rowa + 16) * 1024 + ks * 64 + gg * 16) ^ ((rowa & 7) << 4)));
#pragma unroll
      for (int j = 0; j < 4; j++) {
        acc2[0][j] = __builtin_amdgcn_mfma_f32_16x16x32_bf16(a0, f2[ks % 3][j], acc2[0][j], 0, 0, 0);
        acc2[1][j] = __builtin_amdgcn_mfma_f32_16x16x32_bf16(a1, f2[ks % 3][j], acc2[1][j], 0, 0, 0);
      }
    }
  }

#pragma unroll
  for (int j = 0; j < 4; j++) {
    int col = w * 64 + j * 16 + (lane & 15);
    float bb = bf2[col];
#pragma unroll
    for (int mt = 0; mt < 2; mt++)
#pragma unroll
      for (int r = 0; r < 4; r++) {
        int row = mt * 16 + (lane >> 4) * 4 + r;
        size_t idx = (row0 + row) * DD + col;
        out[idx] = xmid[idx] + acc2[mt][j][r] + bb;
      }
  }
}

extern "C" void kernel_launch(void* const* d_in, const int* in_sizes, int n_in,
                              void* d_out, int out_size, void* d_ws, size_t ws_size,
                              hipStream_t stream) {
  const float* x      = (const float*)d_in[0];
  const int*   knn    = (const int*)  d_in[1];
  const float* relpos = (const float*)d_in[2];
  const float* g1     = (const float*)d_in[3];
  const float* b1     = (const float*)d_in[4];
  const float* g2     = (const float*)d_in[5];
  const float* b2     = (const float*)d_in[6];
  const float* Wq     = (const float*)d_in[7];
  const float* bq     = (const float*)d_in[8];
  const float* Wk     = (const float*)d_in[9];
  const float* bk     = (const float*)d_in[10];
  const float* Wv     = (const float*)d_in[11];
  const float* bv     = (const float*)d_in[12];
  const float* Wo     = (const float*)d_in[13];
  const float* bo     = (const float*)d_in[14];
  const float* Wpa1   = (const float*)d_in[15];
  const float* bpa1   = (const float*)d_in[16];
  const float* Wpa2   = (const float*)d_in[17];
  const float* bpa2   = (const float*)d_in[18];
  const float* Wpv1   = (const float*)d_in[19];
  const float* bpv1   = (const float*)d_in[20];
  const float* Wpv2   = (const float*)d_in[21];
  const float* bpv2   = (const float*)d_in[22];
  const float* Ws1    = (const float*)d_in[23];
  const float* bs1    = (const float*)d_in[24];
  const float* Ws2    = (const float*)d_in[25];
  const float* bs2    = (const float*)d_in[26];
  const float* Wf1    = (const float*)d_in[27];
  const float* bf1    = (const float*)d_in[28];
  const float* Wf2    = (const float*)d_in[29];
  const float* bf2    = (const float*)d_in[30];

  ushort* qb = (ushort*)d_ws;                       // 3 x 8MB bf16 q/k/v
  ushort* kb = qb + (size_t)BB * NN * AA;
  ushort* vb = kb + (size_t)BB * NN * AA;
  float* xmid = (float*)(vb + (size_t)BB * NN * VV);
  ushort* pQKV = (ushort*)(xmid + (size_t)BB * NN * DD);
  ushort* pWf1 = pQKV + 49152;
  ushort* pWf2 = pWf1 + 131072;
  ushort* pS   = pWf2 + 131072;
  ushort* pWo  = pS + 16384;

  k_prep<<<168, 256, 0, stream>>>(Wq, Wk, Wv, Wf1, Wf2, Wpa2, Wpv2, Ws1, Wo, Wpa1, Wpv1,
                                  pQKV, pWf1, pWf2, pS, pWo);
  k_qkv<<<(BB * NN) / 32, 256, 0, stream>>>(x, g1, b1, pQKV, bq, bk, bv, qb, kb, vb);
  k_attn<<<NN / 2, 256, 0, stream>>>(x, relpos, knn, qb, kb, vb,
                                     bpa1, bpa2, bpv1, bpv2,
                                     pS, bs1, Ws2, bs2, pWo, bo, xmid);
  k_ffn<<<(BB * NN) / 32, 256, 0, stream>>>(xmid, g2, b2, pWf1, bf1, pWf2, bf2, (float*)d_out);
}